// Round 22
// baseline (103.284 us; speedup 1.0000x reference)
//
#include <hip/hip_runtime.h>

typedef unsigned short u16;
typedef _Float16 f16;

#define CIN   64
#define HH    128
#define WW    128
#define NPIX  16384   /* HH*WW */
#define HID   256
#define MTOT  512     /* coef(256) + freq(256) stacked */
#define KTOT  576     /* 64 ch * 9 taps */
#define NB    4
#define WELEM 294912  /* MTOT*KTOT */
#define XROW  130     /* padded input grid row */
#define XROWS 16900   /* 130*130 rows per batch */
#define RECB  768     /* YT record: 256 int8 coef + 256 int16 freq */
#define XBLK  265     /* ceil(NB*XROWS/256) blocks for the x-part */

/* index-path constants: must bit-match the f32 trace of the reference */
#define SHM  ((float)(-0.0078125 + 1e-6))
#define SHP  ((float)( 0.0078125 + 1e-6))
#define CLO  ((float)(-1.0 + 1e-6))
#define CHI  ((float)( 1.0 - 1e-6))
#define PIF  3.14159265358979323846f

#define QSCL   1024.0f         /* int16 fixed-point scale (freq) */
#define QISCL  (1.0f / 1024.0f)
#define Q8SCL  16.0f           /* int8 fixed-point scale (coef)  */
#define Q8ISCL 0.0625f

using f32x4 = __attribute__((ext_vector_type(4))) float;
using f16x8 = __attribute__((ext_vector_type(8))) _Float16;

/* ---- async global->LDS DMA (dest = wave base + lane*16) ---- */
typedef __attribute__((address_space(1))) const void gas_void;
typedef __attribute__((address_space(3))) void las_void;
__device__ __forceinline__ void gload16(const void* g, void* l) {
  __builtin_amdgcn_global_load_lds((gas_void*)g, (las_void*)l, 16, 0, 0);
}

__device__ __forceinline__ unsigned packq(float a, float b) {  /* int16 x2 */
  float fa = fminf(fmaxf(a * QSCL, -32767.f), 32767.f);
  float fb = fminf(fmaxf(b * QSCL, -32767.f), 32767.f);
  int ia = (int)rintf(fa), ib = (int)rintf(fb);
  return ((unsigned)(unsigned short)(short)ia) | (((unsigned)(unsigned short)(short)ib) << 16);
}
__device__ __forceinline__ unsigned pack8(float a, float b, float c, float d) { /* int8 x4 */
  int ia = (int)rintf(fminf(fmaxf(a * Q8SCL, -127.f), 127.f));
  int ib = (int)rintf(fminf(fmaxf(b * Q8SCL, -127.f), 127.f));
  int ic = (int)rintf(fminf(fmaxf(c * Q8SCL, -127.f), 127.f));
  int id = (int)rintf(fminf(fmaxf(d * Q8SCL, -127.f), 127.f));
  return (ia & 255) | ((ib & 255) << 8) | ((ic & 255) << 16) | ((id & 255) << 24);
}

/* =====================================================================
 * Kernel 1 (FUSED preps): blocks [0,XBLK) -> xp transpose+pad+swizzle;
 * blocks [XBLK,..) -> weight repack. Validated R20/R21, unchanged.
 * ===================================================================== */
__global__ __launch_bounds__(256) void lte_prep(
    const float* __restrict__ inp, const float* __restrict__ cw,
    const float* __restrict__ fw, f16* __restrict__ xp,
    f16* __restrict__ Awp) {
  if (blockIdx.x < XBLK) {
    int id = blockIdx.x * 256 + threadIdx.x;   /* padded row id */
    if (id >= NB * XROWS) return;
    int b  = id / XROWS;
    int rr = id - b * XROWS;
    int yy = rr / XROW;
    int pc = rr - yy * XROW;      /* padded col 0..129 */
    int x  = pc - 1;
    int y  = yy - 1;
    f16* op = xp + (size_t)id * 64;
    if ((unsigned)y < 128u && (unsigned)x < 128u) {
      const float* ip = inp + (size_t)b * CIN * NPIX + y * WW + x;
      const int p7 = pc & 7;
#pragma unroll
      for (int q = 0; q < 8; ++q) {
        f16x8 v;
#pragma unroll
        for (int k = 0; k < 8; ++k) v[k] = (f16)ip[(((q ^ p7) << 3) + k) * NPIX];
        *(f16x8*)(op + q * 8) = v;
      }
    } else {
      f16x8 z = {};
#pragma unroll
      for (int q = 0; q < 8; ++q) *(f16x8*)(op + q * 8) = z;
    }
  } else {
    int id = (blockIdx.x - XBLK) * 256 + threadIdx.x;
    if (id >= WELEM) return;
    int e  = id & 7;
    int l  = (id >> 3) & 63;
    int mi = (id >> 9) & 3;
    int r  = id >> 11;
    int ks = r & 1;
    int r2 = r >> 1;
    int s  = r2 % 9;
    int q  = r2 / 9;
    int wr = q & 1;
    int mt = q >> 1;
    int m  = mt * 128 + wr * 64 + mi * 16 + (l & 15);
    int ch = (ks * 4 + (l >> 4)) * 8 + e;
    const float* src = (m < HID) ? cw : fw;
    Awp[id] = (f16)src[(m & 255) * KTOT + ch * 9 + s];
  }
}

/* =====================================================================
 * Kernel 2: implicit-im2col GEMM (R21 structure: barrier-free K-loop,
 * B staged once, A 3-deep reg ring, T5 setprio). NEW (T4 counted
 * vmcnt): prologue waits only vmcnt(8) — B rows 1,2 (8-9 newest calls)
 * stay in flight; taps 0-2 need only row 0 (staging loop already
 * issues calls row-ordered). Row 1 gated at h=6 with vmcnt(13), row 2
 * at h=12 with vmcnt(8) (= af-ring depth; all af issued after row 2).
 * Natural outstanding at those points ~12/~8 -> near-zero stall; the
 * ~900cyc full drain before the first MFMA is gone.
 * ===================================================================== */
__global__ __launch_bounds__(256, 3) void lte_conv_gemm(
    const f16* __restrict__ xp, const f16* __restrict__ Awp,
    const float* __restrict__ coef_b, const float* __restrict__ freq_b,
    char* __restrict__ YT) {
  __shared__ f16 Bs[3 * 136 * 64];    /* 52,224 B; reused by epilogue */

  const int t  = threadIdx.x;
  const int bx = blockIdx.x;     /* image row y; pixel tile = [bx*128,+128) */
  const int mt = blockIdx.y;     /* m tile (0..3) */
  const int bb = blockIdx.z;     /* batch */
  const int l  = t & 63;
  const int w  = t >> 6;
  const int wr = __builtin_amdgcn_readfirstlane(w >> 1);
  const int wc = __builtin_amdgcn_readfirstlane(w & 1);
  const int lm = l & 15;

  f32x4 acc[4][4] = {};

  const f16* xb = xp + (size_t)bb * XROWS * 64;
  const f16* Aw = Awp + (size_t)((mt * 2 + wr) * 9) * 4096 + l * 8;

  f16x8 afb[3][4];                 /* 3-deep ring; indices static (unroll) */
#define LOAD_AF(buf_, h_)                                                    \
  {                                                                          \
    const f16* ap_ = Aw + ((h_) >> 1) * 4096 + ((h_) & 1) * 2048;            \
    afb[buf_][0] = *(const f16x8*)(ap_);                                     \
    afb[buf_][1] = *(const f16x8*)(ap_ + 512);                               \
    afb[buf_][2] = *(const f16x8*)(ap_ + 1024);                              \
    afb[buf_][3] = *(const f16x8*)(ap_ + 1536);                              \
  }

  /* af prologue FIRST (oldest in vmcnt order), then B staging in row
     order (c ascending == row ascending: rows are contiguous c-ranges) */
  LOAD_AF(0, 0)
  LOAD_AF(1, 1)
  for (int c = w; c < 51; c += 4) {
    const int rr = c / 17, cc = c - rr * 17;
    gload16(xb + (size_t)((bx + rr) * XROW + cc * 8) * 64 + l * 8,
            Bs + (rr * 136 + cc * 8) * 64);
  }
  /* af(8) + row0 done when <=8 outstanding (rows 1,2 = 8-9 newest) */
  asm volatile("s_waitcnt vmcnt(8)" ::: "memory");
  __builtin_amdgcn_s_barrier();

#pragma unroll
  for (int h = 0; h < 18; ++h) {
    const int s  = h >> 1;
    const int ks = h & 1;
    if (h == 6) {      /* row 1 gate: 13 >= row2(4-5)+... newest only */
      asm volatile("s_waitcnt vmcnt(13)" ::: "memory");
      __builtin_amdgcn_s_barrier();
    }
    if (h == 12) {     /* row 2 gate: 8 = af ring depth (issued after) */
      asm volatile("s_waitcnt vmcnt(8)" ::: "memory");
      __builtin_amdgcn_s_barrier();
    }
    if (h < 16) LOAD_AF((h + 2) % 3, h + 2)          /* 2-deep issue-early */
    const int ky = s / 3, kx = s - 3 * (s / 3);
    const int jl = ks * 4 + (l >> 4);
    f16x8 bg[4];
#pragma unroll
    for (int ni = 0; ni < 4; ++ni) {
      const int xc = wc * 64 + ni * 16 + lm + kx;
      bg[ni] = *(const f16x8*)&Bs[(ky * 136 + xc) * 64 + ((jl ^ (xc & 7)) << 3)];
    }
    __builtin_amdgcn_s_setprio(1);                   /* T5: favor MFMA wave */
#pragma unroll
    for (int mi = 0; mi < 4; ++mi)
#pragma unroll
      for (int ni = 0; ni < 4; ++ni)
        acc[mi][ni] = __builtin_amdgcn_mfma_f32_16x16x32_f16(afb[h % 3][mi], bg[ni], acc[mi][ni], 0, 0, 0);
    __builtin_amdgcn_s_setprio(0);
  }

  /* ---- epilogue: +bias, quantize -> LDS transpose -> coalesced stores.
     mt<2: int8 coef [128][144]; mt>=2: int16 freq [128][138]. ---- */
  __syncthreads();                       /* all waves done reading Bs */
  const float* bias = (mt < 2) ? (coef_b + mt * 128) : (freq_b + (mt - 2) * 128);
  const int rj = (l >> 4) * 4;
  if (mt < 2) {
    char* lt8 = (char*)Bs;               /* [128][144] */
#pragma unroll
    for (int mi = 0; mi < 4; ++mi) {
      const int bm = wr * 64 + mi * 16 + rj;    /* channel 0..127 */
      const float b0 = bias[bm], b1 = bias[bm + 1], b2 = bias[bm + 2], b3 = bias[bm + 3];
#pragma unroll
      for (int ni = 0; ni < 4; ++ni) {
        const int p = wc * 64 + ni * 16 + lm;
        f32x4 v = acc[mi][ni];
        *(unsigned*)&lt8[p * 144 + bm] = pack8(v[0] + b0, v[1] + b1, v[2] + b2, v[3] + b3);
      }
    }
    __syncthreads();
    char* yb8 = YT + (size_t)(bb * NPIX + bx * 128) * RECB + mt * 128;
#pragma unroll
    for (int it = 0; it < 4; ++it) {
      const int p = it * 32 + (t >> 3);
      const int off = (t & 7) * 16;
      uint4 v = *(const uint4*)&lt8[p * 144 + off];
      *(uint4*)&yb8[(size_t)p * RECB + off] = v;
    }
  } else {
    short* lt = (short*)Bs;              /* [128][138] */
#pragma unroll
    for (int mi = 0; mi < 4; ++mi) {
      const int bm = wr * 64 + mi * 16 + rj;
      const float b0 = bias[bm], b1 = bias[bm + 1], b2 = bias[bm + 2], b3 = bias[bm + 3];
#pragma unroll
      for (int ni = 0; ni < 4; ++ni) {
        const int p = wc * 64 + ni * 16 + lm;
        f32x4 v = acc[mi][ni];
        uint2 q2; q2.x = packq(v[0] + b0, v[1] + b1); q2.y = packq(v[2] + b2, v[3] + b3);
        *(uint2*)&lt[p * 138 + bm] = q2;
      }
    }
    __syncthreads();
    short* yb = (short*)(YT + (size_t)(bb * NPIX + bx * 128) * RECB + 256) + (mt - 2) * 128;
    const int lp = l >> 5;
    const int c4 = (l & 31) * 4;
#pragma unroll
    for (int it = 0; it < 16; ++it) {
      const int p = it * 8 + w * 2 + lp;
      uint2 v = *(const uint2*)&lt[p * 138 + c4];
      *(uint2*)&yb[(size_t)p * (RECB / 2) + c4] = v;
    }
  }
}

/* =====================================================================
 * Kernel 3: 4-corner nearest sample + sin/cos modulation.
 * R21 structure (validated): block-shared geometry + __sincosf.
 * Index path bit-exact — unchanged.
 * ===================================================================== */
__global__ __launch_bounds__(256) void lte_sample(
    const char* __restrict__ YT, const float* __restrict__ coord,
    const float* __restrict__ cell, const float* __restrict__ phase_w,
    float* __restrict__ out) {
  __shared__ float lout[256 * 17];
  __shared__ float geo[16][16];
  const int tid   = threadIdx.x;          /* 0..255 */
  const int j     = tid & 127;            /* channel lane */
  const int qh    = tid >> 7;             /* query half: 0 or 1 */
  const int q0    = blockIdx.x * 16;      /* global over B*Q */
  const int b     = q0 >> 14;
  const int q0loc = q0 & (NPIX - 1);
  const float pw0 = phase_w[2 * j], pw1 = phase_w[2 * j + 1];
  const char* Yb = YT + (size_t)b * NPIX * RECB;

  /* ---- geometry: one thread per query, bit-exact index path ---- */
  if (tid < 16) {
    const int qg = q0 + tid;
    const float c0  = coord[2 * qg], c1 = coord[2 * qg + 1];
    const float ce0 = cell[2 * qg],  ce1 = cell[2 * qg + 1];
    float tot = 0.f, a3 = 0.f;
    float* g = &geo[tid][0];
#pragma unroll
    for (int ci = 0; ci < 4; ++ci) {     /* (vx,vy): (-,-),(-,+),(+,-),(+,+) */
      const float s0 = (ci & 2) ? SHP : SHM;
      const float s1 = (ci & 1) ? SHP : SHM;
      float cx = fminf(fmaxf(c0 + s0, CLO), CHI);
      float cy = fminf(fmaxf(c1 + s1, CLO), CHI);
      float ty = ((cx + 1.0f) * 128.0f - 1.0f) * 0.5f;
      float tx = ((cy + 1.0f) * 128.0f - 1.0f) * 0.5f;
      float fy = fminf(fmaxf(rintf(ty), 0.f), 127.f);   /* round half-even */
      float fx = fminf(fmaxf(rintf(tx), 0.f), 127.f);
      int iy = (int)fy, ix = (int)fx;
      float qcy = -1.0f + (2.0f * fy + 1.0f) * (1.0f / 128.0f);
      float qcx = -1.0f + (2.0f * fx + 1.0f) * (1.0f / 128.0f);
      float r0 = (c0 - qcy) * 128.0f;
      float r1 = (c1 - qcx) * 128.0f;
      float ar = fabsf(r0 * r1);
      tot += ar + 1e-9f;
      if (ci == 3) a3 = ar;
      ((int*)g)[ci] = (iy * 128 + ix) * RECB;
      g[4 + ci] = r0;
      g[8 + ci] = r1;
    }
    g[12] = a3 / tot;
    g[13] = ce0 * 128.0f;
    g[14] = ce1 * 128.0f;
  }
  __syncthreads();

  for (int qq = 0; qq < 2; ++qq) {        /* 2 quads of 4 queries per half */
    int rA[4][4], rB[4][4], rU[4][4];
#pragma unroll
    for (int qi = 0; qi < 4; ++qi) {
      const int* go = (const int*)&geo[qh * 8 + qq * 4 + qi][0];
#pragma unroll
      for (int ci = 0; ci < 4; ++ci) {
        const char* bp = Yb + go[ci];
        rA[qi][ci] = (int)*(const signed char*)(bp + j);
        rB[qi][ci] = (int)*(const signed char*)(bp + 128 + j);
        rU[qi][ci] = *(const int*)(bp + 256 + 4 * j);
      }
    }
#pragma unroll
    for (int qi = 0; qi < 4; ++qi) {
      const float* g = &geo[qh * 8 + qq * 4 + qi][0];
      const float ph = g[13] * pw0 + g[14] * pw1;
      float accC = 0.f, accS = 0.f;
#pragma unroll
      for (int ci = 0; ci < 4; ++ci) {
        float coefA = (float)rA[qi][ci] * Q8ISCL;
        float coefB = (float)rB[qi][ci] * Q8ISCL;
        int u = rU[qi][ci];
        float f0 = (float)((short)(u & 0xFFFF)) * QISCL;
        float f1 = (float)((short)(u >> 16)) * QISCL;
        float f = f0 * g[4 + ci] + f1 * g[8 + ci] + ph;
        float sv, cv;
        __sincosf(PIF * f, &sv, &cv);
        accC += coefA * cv;
        accS += coefB * sv;
      }
      const float wgt = g[12];
      const int col = qh * 8 + qq * 4 + qi;
      lout[j * 17 + col]         = accC * wgt;
      lout[(j + 128) * 17 + col] = accS * wgt;
    }
  }
  __syncthreads();
#pragma unroll
  for (int pass = 0; pass < 4; ++pass) {
    int c  = pass * 64 + (tid >> 2);
    int qf = (tid & 3) * 4;
    float4 v;
    v.x = lout[c * 17 + qf];     v.y = lout[c * 17 + qf + 1];
    v.z = lout[c * 17 + qf + 2]; v.w = lout[c * 17 + qf + 3];
    *(float4*)(out + (((size_t)(b * 256 + c)) << 14) + q0loc + qf) = v;
  }
}

extern "C" void kernel_launch(void* const* d_in, const int* in_sizes, int n_in,
                              void* d_out, int out_size, void* d_ws, size_t ws_size,
                              hipStream_t stream) {
  const float* inp     = (const float*)d_in[0];
  const float* coord   = (const float*)d_in[1];
  const float* cell    = (const float*)d_in[2];
  const float* coef_w  = (const float*)d_in[3];
  const float* coef_b  = (const float*)d_in[4];
  const float* freq_w  = (const float*)d_in[5];
  const float* freq_b  = (const float*)d_in[6];
  const float* phase_w = (const float*)d_in[7];
  float* out = (float*)d_out;

  /* ws: Awp fp16 (0.59MB) | xp_pad fp16 (8.65MB + slack) | YT 768B-rec (50.3MB) */
  f16* Awp = (f16*)d_ws;
  f16* xp  = (f16*)((char*)d_ws + (size_t)WELEM * 2);
  char* YT = (char*)d_ws + (size_t)WELEM * 2 + ((size_t)NB * XROWS + 8) * 64 * 2;

  lte_prep<<<dim3(XBLK + 1152), dim3(256), 0, stream>>>(inp, coef_w, freq_w, xp, Awp);
  lte_conv_gemm<<<dim3(128, 4, 4), dim3(256), 0, stream>>>(xp, Awp, coef_b, freq_b, YT);
  lte_sample<<<dim3(4096), dim3(256), 0, stream>>>(YT, coord, cell, phase_w, out);
}

// Round 23
// 101.188 us; speedup vs baseline: 1.0207x; 1.0207x over previous
//
#include <hip/hip_runtime.h>

typedef unsigned short u16;
typedef _Float16 f16;

#define CIN   64
#define HH    128
#define WW    128
#define NPIX  16384   /* HH*WW */
#define HID   256
#define MTOT  512     /* coef(256) + freq(256) stacked */
#define KTOT  576     /* 64 ch * 9 taps */
#define NB    4
#define WELEM 294912  /* MTOT*KTOT */
#define XROW  130     /* padded input grid row */
#define XROWS 16900   /* 130*130 rows per batch */
#define RECB  768     /* YT record: 256 int8 coef + 256 int16 freq */
#define XBLK  265     /* ceil(NB*XROWS/256) blocks for the x-part */

/* index-path constants: must bit-match the f32 trace of the reference */
#define SHM  ((float)(-0.0078125 + 1e-6))
#define SHP  ((float)( 0.0078125 + 1e-6))
#define CLO  ((float)(-1.0 + 1e-6))
#define CHI  ((float)( 1.0 - 1e-6))
#define PIF  3.14159265358979323846f

#define QSCL   1024.0f         /* int16 fixed-point scale (freq) */
#define QISCL  (1.0f / 1024.0f)
#define Q8SCL  16.0f           /* int8 fixed-point scale (coef)  */
#define Q8ISCL 0.0625f

using f32x4 = __attribute__((ext_vector_type(4))) float;
using f16x8 = __attribute__((ext_vector_type(8))) _Float16;

/* ---- async global->LDS DMA (dest = wave base + lane*16) ---- */
typedef __attribute__((address_space(1))) const void gas_void;
typedef __attribute__((address_space(3))) void las_void;
__device__ __forceinline__ void gload16(const void* g, void* l) {
  __builtin_amdgcn_global_load_lds((gas_void*)g, (las_void*)l, 16, 0, 0);
}

__device__ __forceinline__ unsigned packq(float a, float b) {  /* int16 x2 */
  float fa = fminf(fmaxf(a * QSCL, -32767.f), 32767.f);
  float fb = fminf(fmaxf(b * QSCL, -32767.f), 32767.f);
  int ia = (int)rintf(fa), ib = (int)rintf(fb);
  return ((unsigned)(unsigned short)(short)ia) | (((unsigned)(unsigned short)(short)ib) << 16);
}
__device__ __forceinline__ unsigned pack8(float a, float b, float c, float d) { /* int8 x4 */
  int ia = (int)rintf(fminf(fmaxf(a * Q8SCL, -127.f), 127.f));
  int ib = (int)rintf(fminf(fmaxf(b * Q8SCL, -127.f), 127.f));
  int ic = (int)rintf(fminf(fmaxf(c * Q8SCL, -127.f), 127.f));
  int id = (int)rintf(fminf(fmaxf(d * Q8SCL, -127.f), 127.f));
  return (ia & 255) | ((ib & 255) << 8) | ((ic & 255) << 16) | ((id & 255) << 24);
}

/* =====================================================================
 * Kernel 1 (FUSED preps): blocks [0,XBLK) -> xp transpose+pad+swizzle;
 * blocks [XBLK,..) -> weight repack. Validated R20/R21.
 * ===================================================================== */
__global__ __launch_bounds__(256) void lte_prep(
    const float* __restrict__ inp, const float* __restrict__ cw,
    const float* __restrict__ fw, f16* __restrict__ xp,
    f16* __restrict__ Awp) {
  if (blockIdx.x < XBLK) {
    int id = blockIdx.x * 256 + threadIdx.x;   /* padded row id */
    if (id >= NB * XROWS) return;
    int b  = id / XROWS;
    int rr = id - b * XROWS;
    int yy = rr / XROW;
    int pc = rr - yy * XROW;      /* padded col 0..129 */
    int x  = pc - 1;
    int y  = yy - 1;
    f16* op = xp + (size_t)id * 64;
    if ((unsigned)y < 128u && (unsigned)x < 128u) {
      const float* ip = inp + (size_t)b * CIN * NPIX + y * WW + x;
      const int p7 = pc & 7;
#pragma unroll
      for (int q = 0; q < 8; ++q) {
        f16x8 v;
#pragma unroll
        for (int k = 0; k < 8; ++k) v[k] = (f16)ip[(((q ^ p7) << 3) + k) * NPIX];
        *(f16x8*)(op + q * 8) = v;
      }
    } else {
      f16x8 z = {};
#pragma unroll
      for (int q = 0; q < 8; ++q) *(f16x8*)(op + q * 8) = z;
    }
  } else {
    int id = (blockIdx.x - XBLK) * 256 + threadIdx.x;
    if (id >= WELEM) return;
    int e  = id & 7;
    int l  = (id >> 3) & 63;
    int mi = (id >> 9) & 3;
    int r  = id >> 11;
    int ks = r & 1;
    int r2 = r >> 1;
    int s  = r2 % 9;
    int q  = r2 / 9;
    int wr = q & 1;
    int mt = q >> 1;
    int m  = mt * 128 + wr * 64 + mi * 16 + (l & 15);
    int ch = (ks * 4 + (l >> 4)) * 8 + e;
    const float* src = (m < HID) ? cw : fw;
    Awp[id] = (f16)src[(m & 255) * KTOT + ch * 9 + s];
  }
}

/* =====================================================================
 * Kernel 2: implicit-im2col GEMM (validated best, R20/R21): 128x128
 * tile, 4 waves, barrier-free K-loop, B staged once (52KB LDS), A
 * 3-deep reg ring, T5 setprio around MFMA cluster.
 * ===================================================================== */
__global__ __launch_bounds__(256, 3) void lte_conv_gemm(
    const f16* __restrict__ xp, const f16* __restrict__ Awp,
    const float* __restrict__ coef_b, const float* __restrict__ freq_b,
    char* __restrict__ YT) {
  __shared__ f16 Bs[3 * 136 * 64];    /* 52,224 B; reused by epilogue */

  const int t  = threadIdx.x;
  const int bx = blockIdx.x;     /* image row y; pixel tile = [bx*128,+128) */
  const int mt = blockIdx.y;     /* m tile (0..3) */
  const int bb = blockIdx.z;     /* batch */
  const int l  = t & 63;
  const int w  = t >> 6;
  const int wr = __builtin_amdgcn_readfirstlane(w >> 1);
  const int wc = __builtin_amdgcn_readfirstlane(w & 1);
  const int lm = l & 15;

  f32x4 acc[4][4] = {};

  const f16* xb = xp + (size_t)bb * XROWS * 64;
  const f16* Aw = Awp + (size_t)((mt * 2 + wr) * 9) * 4096 + l * 8;

  /* ---- prologue: stage B rows bx-1..bx+1, 51 x 1KB DMA calls ---- */
  for (int c = w; c < 51; c += 4) {
    const int rr = c / 17, cc = c - rr * 17;
    gload16(xb + (size_t)((bx + rr) * XROW + cc * 8) * 64 + l * 8,
            Bs + (rr * 136 + cc * 8) * 64);
  }

  f16x8 afb[3][4];                 /* 3-deep ring; indices static (unroll) */
#define LOAD_AF(buf_, h_)                                                    \
  {                                                                          \
    const f16* ap_ = Aw + ((h_) >> 1) * 4096 + ((h_) & 1) * 2048;            \
    afb[buf_][0] = *(const f16x8*)(ap_);                                     \
    afb[buf_][1] = *(const f16x8*)(ap_ + 512);                               \
    afb[buf_][2] = *(const f16x8*)(ap_ + 1024);                              \
    afb[buf_][3] = *(const f16x8*)(ap_ + 1536);                              \
  }

  LOAD_AF(0, 0)
  LOAD_AF(1, 1)
  asm volatile("s_waitcnt vmcnt(0)" ::: "memory");
  __builtin_amdgcn_s_barrier();

#pragma unroll
  for (int h = 0; h < 18; ++h) {
    const int s  = h >> 1;
    const int ks = h & 1;
    if (h < 16) LOAD_AF((h + 2) % 3, h + 2)          /* 2-deep issue-early */
    const int ky = s / 3, kx = s - 3 * (s / 3);
    const int jl = ks * 4 + (l >> 4);
    f16x8 bg[4];
#pragma unroll
    for (int ni = 0; ni < 4; ++ni) {
      const int xc = wc * 64 + ni * 16 + lm + kx;
      bg[ni] = *(const f16x8*)&Bs[(ky * 136 + xc) * 64 + ((jl ^ (xc & 7)) << 3)];
    }
    __builtin_amdgcn_s_setprio(1);                   /* T5: favor MFMA wave */
#pragma unroll
    for (int mi = 0; mi < 4; ++mi)
#pragma unroll
      for (int ni = 0; ni < 4; ++ni)
        acc[mi][ni] = __builtin_amdgcn_mfma_f32_16x16x32_f16(afb[h % 3][mi], bg[ni], acc[mi][ni], 0, 0, 0);
    __builtin_amdgcn_s_setprio(0);
  }

  /* ---- epilogue: +bias, quantize -> LDS transpose -> coalesced stores.
     mt<2: int8 coef [128][144]; mt>=2: int16 freq [128][138]. ---- */
  __syncthreads();                       /* all waves done reading Bs */
  const float* bias = (mt < 2) ? (coef_b + mt * 128) : (freq_b + (mt - 2) * 128);
  const int rj = (l >> 4) * 4;
  if (mt < 2) {
    char* lt8 = (char*)Bs;               /* [128][144] */
#pragma unroll
    for (int mi = 0; mi < 4; ++mi) {
      const int bm = wr * 64 + mi * 16 + rj;    /* channel 0..127 */
      const float b0 = bias[bm], b1 = bias[bm + 1], b2 = bias[bm + 2], b3 = bias[bm + 3];
#pragma unroll
      for (int ni = 0; ni < 4; ++ni) {
        const int p = wc * 64 + ni * 16 + lm;
        f32x4 v = acc[mi][ni];
        *(unsigned*)&lt8[p * 144 + bm] = pack8(v[0] + b0, v[1] + b1, v[2] + b2, v[3] + b3);
      }
    }
    __syncthreads();
    char* yb8 = YT + (size_t)(bb * NPIX + bx * 128) * RECB + mt * 128;
#pragma unroll
    for (int it = 0; it < 4; ++it) {
      const int p = it * 32 + (t >> 3);
      const int off = (t & 7) * 16;
      uint4 v = *(const uint4*)&lt8[p * 144 + off];
      *(uint4*)&yb8[(size_t)p * RECB + off] = v;
    }
  } else {
    short* lt = (short*)Bs;              /* [128][138] */
#pragma unroll
    for (int mi = 0; mi < 4; ++mi) {
      const int bm = wr * 64 + mi * 16 + rj;
      const float b0 = bias[bm], b1 = bias[bm + 1], b2 = bias[bm + 2], b3 = bias[bm + 3];
#pragma unroll
      for (int ni = 0; ni < 4; ++ni) {
        const int p = wc * 64 + ni * 16 + lm;
        f32x4 v = acc[mi][ni];
        uint2 q2; q2.x = packq(v[0] + b0, v[1] + b1); q2.y = packq(v[2] + b2, v[3] + b3);
        *(uint2*)&lt[p * 138 + bm] = q2;
      }
    }
    __syncthreads();
    short* yb = (short*)(YT + (size_t)(bb * NPIX + bx * 128) * RECB + 256) + (mt - 2) * 128;
    const int lp = l >> 5;
    const int c4 = (l & 31) * 4;
#pragma unroll
    for (int it = 0; it < 16; ++it) {
      const int p = it * 8 + w * 2 + lp;
      uint2 v = *(const uint2*)&lt[p * 138 + c4];
      *(uint2*)&yb[(size_t)p * (RECB / 2) + c4] = v;
    }
  }
}

/* =====================================================================
 * Kernel 3: 4-corner nearest sample + sin/cos modulation (validated
 * R21): block-shared geometry (threads 0..15 compute index math once,
 * bit-exact) + __sincosf. Gather/output structure R17-R21.
 * ===================================================================== */
__global__ __launch_bounds__(256) void lte_sample(
    const char* __restrict__ YT, const float* __restrict__ coord,
    const float* __restrict__ cell, const float* __restrict__ phase_w,
    float* __restrict__ out) {
  __shared__ float lout[256 * 17];
  __shared__ float geo[16][16];
  const int tid   = threadIdx.x;          /* 0..255 */
  const int j     = tid & 127;            /* channel lane */
  const int qh    = tid >> 7;             /* query half: 0 or 1 */
  const int q0    = blockIdx.x * 16;      /* global over B*Q */
  const int b     = q0 >> 14;
  const int q0loc = q0 & (NPIX - 1);
  const float pw0 = phase_w[2 * j], pw1 = phase_w[2 * j + 1];
  const char* Yb = YT + (size_t)b * NPIX * RECB;

  /* ---- geometry: one thread per query, bit-exact index path ---- */
  if (tid < 16) {
    const int qg = q0 + tid;
    const float c0  = coord[2 * qg], c1 = coord[2 * qg + 1];
    const float ce0 = cell[2 * qg],  ce1 = cell[2 * qg + 1];
    float tot = 0.f, a3 = 0.f;
    float* g = &geo[tid][0];
#pragma unroll
    for (int ci = 0; ci < 4; ++ci) {     /* (vx,vy): (-,-),(-,+),(+,-),(+,+) */
      const float s0 = (ci & 2) ? SHP : SHM;
      const float s1 = (ci & 1) ? SHP : SHM;
      float cx = fminf(fmaxf(c0 + s0, CLO), CHI);
      float cy = fminf(fmaxf(c1 + s1, CLO), CHI);
      float ty = ((cx + 1.0f) * 128.0f - 1.0f) * 0.5f;
      float tx = ((cy + 1.0f) * 128.0f - 1.0f) * 0.5f;
      float fy = fminf(fmaxf(rintf(ty), 0.f), 127.f);   /* round half-even */
      float fx = fminf(fmaxf(rintf(tx), 0.f), 127.f);
      int iy = (int)fy, ix = (int)fx;
      float qcy = -1.0f + (2.0f * fy + 1.0f) * (1.0f / 128.0f);
      float qcx = -1.0f + (2.0f * fx + 1.0f) * (1.0f / 128.0f);
      float r0 = (c0 - qcy) * 128.0f;
      float r1 = (c1 - qcx) * 128.0f;
      float ar = fabsf(r0 * r1);
      tot += ar + 1e-9f;
      if (ci == 3) a3 = ar;
      ((int*)g)[ci] = (iy * 128 + ix) * RECB;
      g[4 + ci] = r0;
      g[8 + ci] = r1;
    }
    g[12] = a3 / tot;
    g[13] = ce0 * 128.0f;
    g[14] = ce1 * 128.0f;
  }
  __syncthreads();

  for (int qq = 0; qq < 2; ++qq) {        /* 2 quads of 4 queries per half */
    int rA[4][4], rB[4][4], rU[4][4];
#pragma unroll
    for (int qi = 0; qi < 4; ++qi) {
      const int* go = (const int*)&geo[qh * 8 + qq * 4 + qi][0];
#pragma unroll
      for (int ci = 0; ci < 4; ++ci) {
        const char* bp = Yb + go[ci];
        rA[qi][ci] = (int)*(const signed char*)(bp + j);
        rB[qi][ci] = (int)*(const signed char*)(bp + 128 + j);
        rU[qi][ci] = *(const int*)(bp + 256 + 4 * j);
      }
    }
#pragma unroll
    for (int qi = 0; qi < 4; ++qi) {
      const float* g = &geo[qh * 8 + qq * 4 + qi][0];
      const float ph = g[13] * pw0 + g[14] * pw1;
      float accC = 0.f, accS = 0.f;
#pragma unroll
      for (int ci = 0; ci < 4; ++ci) {
        float coefA = (float)rA[qi][ci] * Q8ISCL;
        float coefB = (float)rB[qi][ci] * Q8ISCL;
        int u = rU[qi][ci];
        float f0 = (float)((short)(u & 0xFFFF)) * QISCL;
        float f1 = (float)((short)(u >> 16)) * QISCL;
        float f = f0 * g[4 + ci] + f1 * g[8 + ci] + ph;
        float sv, cv;
        __sincosf(PIF * f, &sv, &cv);
        accC += coefA * cv;
        accS += coefB * sv;
      }
      const float wgt = g[12];
      const int col = qh * 8 + qq * 4 + qi;
      lout[j * 17 + col]         = accC * wgt;
      lout[(j + 128) * 17 + col] = accS * wgt;
    }
  }
  __syncthreads();
#pragma unroll
  for (int pass = 0; pass < 4; ++pass) {
    int c  = pass * 64 + (tid >> 2);
    int qf = (tid & 3) * 4;
    float4 v;
    v.x = lout[c * 17 + qf];     v.y = lout[c * 17 + qf + 1];
    v.z = lout[c * 17 + qf + 2]; v.w = lout[c * 17 + qf + 3];
    *(float4*)(out + (((size_t)(b * 256 + c)) << 14) + q0loc + qf) = v;
  }
}

extern "C" void kernel_launch(void* const* d_in, const int* in_sizes, int n_in,
                              void* d_out, int out_size, void* d_ws, size_t ws_size,
                              hipStream_t stream) {
  const float* inp     = (const float*)d_in[0];
  const float* coord   = (const float*)d_in[1];
  const float* cell    = (const float*)d_in[2];
  const float* coef_w  = (const float*)d_in[3];
  const float* coef_b  = (const float*)d_in[4];
  const float* freq_w  = (const float*)d_in[5];
  const float* freq_b  = (const float*)d_in[6];
  const float* phase_w = (const float*)d_in[7];
  float* out = (float*)d_out;

  /* ws: Awp fp16 (0.59MB) | xp_pad fp16 (8.65MB + slack) | YT 768B-rec (50.3MB) */
  f16* Awp = (f16*)d_ws;
  f16* xp  = (f16*)((char*)d_ws + (size_t)WELEM * 2);
  char* YT = (char*)d_ws + (size_t)WELEM * 2 + ((size_t)NB * XROWS + 8) * 64 * 2;

  lte_prep<<<dim3(XBLK + 1152), dim3(256), 0, stream>>>(inp, coef_w, freq_w, xp, Awp);
  lte_conv_gemm<<<dim3(128, 4, 4), dim3(256), 0, stream>>>(xp, Awp, coef_b, freq_b, YT);
  lte_sample<<<dim3(4096), dim3(256), 0, stream>>>(YT, coord, cell, phase_w, out);
}